// Round 3
// baseline (174.045 us; speedup 1.0000x reference)
//
#include <hip/hip_runtime.h>
#include <stdint.h>

#define LEN 512
#define NB 64
#define NCX 64
#define NCV 4
#define NCU 4

typedef float f4 __attribute__((ext_vector_type(4)));

// ---------------- Threefry-2x32, 20 rounds, key = (0, 42) ----------------
__device__ __forceinline__ uint32_t rotl32(uint32_t v, int r) {
  return (v << r) | (v >> (32 - r));
}

__device__ __forceinline__ void threefry2x32_k042(uint32_t c0, uint32_t c1,
                                                  uint32_t& o0, uint32_t& o1) {
  const uint32_t ks0 = 0u, ks1 = 42u;
  const uint32_t ks2 = 0u ^ 42u ^ 0x1BD11BDAu;
  uint32_t x0 = c0 + ks0;
  uint32_t x1 = c1 + ks1;
#define TF_ROUND(R) { x0 += x1; x1 = rotl32(x1, R); x1 ^= x0; }
  TF_ROUND(13) TF_ROUND(15) TF_ROUND(26) TF_ROUND(6)
  x0 += ks1; x1 += ks2 + 1u;
  TF_ROUND(17) TF_ROUND(29) TF_ROUND(16) TF_ROUND(24)
  x0 += ks2; x1 += ks0 + 2u;
  TF_ROUND(13) TF_ROUND(15) TF_ROUND(26) TF_ROUND(6)
  x0 += ks0; x1 += ks1 + 3u;
  TF_ROUND(17) TF_ROUND(29) TF_ROUND(16) TF_ROUND(24)
  x0 += ks1; x1 += ks2 + 4u;
  TF_ROUND(13) TF_ROUND(15) TF_ROUND(26) TF_ROUND(6)
  x0 += ks2; x1 += ks0 + 5u;
#undef TF_ROUND
  o0 = x0; o1 = x1;
}

// ---------------- Kernel 1: build permutation, ml, mask_p ----------------
// perm semantics (matches jnp.argsort(-rand) stable ascending):
//   positions [0, n_inv): invalid slots ordered by rand DESC, ties idx ASC
//   positions [n_inv, L): valid slots in original index order
// Rank loop runs only over the compacted invalid list (n_inv entries),
// built order-preserving via ballot prefix sums.
__global__ __launch_bounds__(LEN) void build_perm(const void* __restrict__ mask,
                                                  int* __restrict__ src,
                                                  int* __restrict__ ml_arr,
                                                  float* __restrict__ mask_out) {
  const int b = blockIdx.x;
  const int l = threadIdx.x;
  const int wave = l >> 6, lane = l & 63;
  __shared__ uint32_t inv_key[LEN];
  __shared__ int inv_idx[LEN];
  __shared__ int wsum[8];
  __shared__ int woff[9];

  // runtime mask-dtype detection: first element is always valid (len >= 256)
  const uint32_t w0 = ((const uint32_t*)mask)[0];
  bool valid;
  if (w0 == 1u) {                       // int32 0/1
    valid = ((const int*)mask)[b * LEN + l] != 0;
  } else if (w0 == 0x3F800000u) {       // float32 0.0/1.0
    valid = ((const float*)mask)[b * LEN + l] != 0.0f;
  } else {                              // 1-byte bool
    valid = ((const unsigned char*)mask)[b * LEN + l] != 0;
  }
  const bool inv = !valid;

  uint32_t o0, o1;
  threefry2x32_k042(0u, (uint32_t)(b * LEN + l), o0, o1);
  const uint32_t bits = o0 ^ o1;
  const uint32_t ui = (bits >> 9) | 0x3F800000u;  // monotone in uniform value

  // order-preserving compaction of invalid slots
  const unsigned long long bal = __ballot(inv);
  const int lower = __popcll(bal & ((1ull << lane) - 1ull));
  if (lane == 0) wsum[wave] = __popcll(bal);
  __syncthreads();
  if (l == 0) {
    int acc = 0;
    for (int w = 0; w < 8; ++w) { woff[w] = acc; acc += wsum[w]; }
    woff[8] = acc;
  }
  __syncthreads();
  const int n_inv = woff[8];
  const int inv_before = woff[wave] + lower;  // # invalid with index < l
  if (inv) {
    inv_key[inv_before] = ui;
    inv_idx[inv_before] = l;
  }
  __syncthreads();

  int pos;
  if (inv) {
    int rank = 0;
    for (int j = 0; j < n_inv; ++j) {
      const uint32_t kj = inv_key[j];
      rank += (kj > ui || (kj == ui && inv_idx[j] < l)) ? 1 : 0;
    }
    pos = rank;
  } else {
    pos = n_inv + (l - inv_before);  // valid slots keep original order
  }
  src[b * LEN + pos] = l;

  const int nv = LEN - n_inv;
  const int ml = nv < 1 ? 1 : nv;
  if (l == 0) ml_arr[b] = ml;
  mask_out[b * LEN + l] = (l >= n_inv && l < ml) ? 1.0f : 0.0f;
}

// ---------------- Kernel 2: gather + trim for x and v (fused) ----------------
__global__ void gather_xv(const float* __restrict__ xin, const float* __restrict__ vin,
                          float* __restrict__ xout, float* __restrict__ vout,
                          const int* __restrict__ src, const int* __restrict__ ml_arr) {
  int idx = blockIdx.x * blockDim.x + threadIdx.x;
  const float* in;
  float* out;
  int log2C;
  if (idx < NB * NCX * LEN) {
    in = xin; out = xout; log2C = 6;
  } else {
    idx -= NB * NCX * LEN;
    in = vin; out = vout; log2C = 2;
  }
  const int p = idx & (LEN - 1);
  const int bc = idx >> 9;
  const int b = bc >> log2C;
  float val = 0.0f;
  if (p < ml_arr[b]) {
    val = in[(bc << 9) + src[b * LEN + p]];
  }
  out[idx] = val;
}

// ---------------- Kernel 3: uu[b,c,perm[i],perm[j]] ----------------
// Wave-private rows: each 64-lane wave stages one full 2KB input row in its
// own LDS slice (8 floats/lane), then gathers columns via indices hoisted to
// registers. Same-wave DS ops complete in order -> NO barriers, NO vmcnt
// drains in the row loop; waves pipeline independently. NT hints keep the
// 512MB streaming traffic out of L2's way.
__global__ __launch_bounds__(256) void uu_perm(const float* __restrict__ in,
                                               float* __restrict__ out,
                                               const int* __restrict__ src) {
  __shared__ int s_src[LEN];
  __shared__ float s_row[4][LEN];
  const int tid = threadIdx.x;
  const int wave = tid >> 6, lane = tid & 63;
  const int b = blockIdx.x >> 6;               // 64 blocks per batch sample
  const int row0 = blockIdx.x * 32 + wave * 8; // 8 rows per wave
  const int i0 = row0 & (LEN - 1);
  const long plane = (long)(row0 & ~(LEN - 1)) * LEN;

  for (int t = tid; t < LEN; t += 256) s_src[t] = src[b * LEN + t];
  __syncthreads();  // the only barrier

  // column gather sources (same for all 8 rows) -> registers
  int c[8];
#pragma unroll
  for (int k = 0; k < 8; ++k) c[k] = s_src[lane * 8 + k];
  // input row ids -> registers
  int rs[8];
#pragma unroll
  for (int r = 0; r < 8; ++r) rs[r] = s_src[i0 + r];

  float* myrow = &s_row[wave][0];

#pragma unroll
  for (int r = 0; r < 8; ++r) {
    const f4* rp = (const f4*)(in + plane + (long)rs[r] * LEN + lane * 8);
    const f4 a0 = __builtin_nontemporal_load(rp);
    const f4 a1 = __builtin_nontemporal_load(rp + 1);
    *(f4*)(myrow + lane * 8) = a0;
    *(f4*)(myrow + lane * 8 + 4) = a1;
    f4 q0, q1;
    q0.x = myrow[c[0]]; q0.y = myrow[c[1]]; q0.z = myrow[c[2]]; q0.w = myrow[c[3]];
    q1.x = myrow[c[4]]; q1.y = myrow[c[5]]; q1.z = myrow[c[6]]; q1.w = myrow[c[7]];
    f4* op = (f4*)(out + (long)(row0 + r) * LEN + lane * 8);
    __builtin_nontemporal_store(q0, op);
    __builtin_nontemporal_store(q1, op + 1);
  }
}

extern "C" void kernel_launch(void* const* d_in, const int* in_sizes, int n_in,
                              void* d_out, int out_size, void* d_ws, size_t ws_size,
                              hipStream_t stream) {
  const float* x  = (const float*)d_in[0];   // (64,64,512)
  const float* v  = (const float*)d_in[1];   // (64,4,512)
  const float* uu = (const float*)d_in[2];   // (64,4,512,512)
  const void*  mask = d_in[3];               // (64,1,512)

  float* out   = (float*)d_out;
  float* out_x = out;                        // 2,097,152
  float* out_v = out + 2097152;              // 131,072
  float* out_m = out + 2228224;              // 32,768
  float* out_u = out + 2260992;              // 67,108,864

  int* src = (int*)d_ws;                     // 64*512 ints
  int* ml  = src + NB * LEN;                 // 64 ints

  build_perm<<<NB, LEN, 0, stream>>>(mask, src, ml, out_m);

  const int total_xv = NB * NCX * LEN + NB * NCV * LEN;  // 2,228,224
  gather_xv<<<(total_xv + 255) / 256, 256, 0, stream>>>(x, v, out_x, out_v, src, ml);

  uu_perm<<<(NB * NCU * LEN) / 32, 256, 0, stream>>>(uu, out_u, src);
}

// Round 4
// 132.687 us; speedup vs baseline: 1.3117x; 1.3117x over previous
//
#include <hip/hip_runtime.h>
#include <stdint.h>

#define LEN 512
#define NB 64
#define NCX 64
#define NCV 4
#define NCU 4

typedef float f4 __attribute__((ext_vector_type(4)));

// ---------------- Threefry-2x32, 20 rounds, key = (0, 42) ----------------
__device__ __forceinline__ uint32_t rotl32(uint32_t v, int r) {
  return (v << r) | (v >> (32 - r));
}

__device__ __forceinline__ void threefry2x32_k042(uint32_t c0, uint32_t c1,
                                                  uint32_t& o0, uint32_t& o1) {
  const uint32_t ks0 = 0u, ks1 = 42u;
  const uint32_t ks2 = 0u ^ 42u ^ 0x1BD11BDAu;
  uint32_t x0 = c0 + ks0;
  uint32_t x1 = c1 + ks1;
#define TF_ROUND(R) { x0 += x1; x1 = rotl32(x1, R); x1 ^= x0; }
  TF_ROUND(13) TF_ROUND(15) TF_ROUND(26) TF_ROUND(6)
  x0 += ks1; x1 += ks2 + 1u;
  TF_ROUND(17) TF_ROUND(29) TF_ROUND(16) TF_ROUND(24)
  x0 += ks2; x1 += ks0 + 2u;
  TF_ROUND(13) TF_ROUND(15) TF_ROUND(26) TF_ROUND(6)
  x0 += ks0; x1 += ks1 + 3u;
  TF_ROUND(17) TF_ROUND(29) TF_ROUND(16) TF_ROUND(24)
  x0 += ks1; x1 += ks2 + 4u;
  TF_ROUND(13) TF_ROUND(15) TF_ROUND(26) TF_ROUND(6)
  x0 += ks2; x1 += ks0 + 5u;
#undef TF_ROUND
  o0 = x0; o1 = x1;
}

// ---------------- Kernel 1: permutation (fwd + inverse), ml, mask_p -------
// perm semantics (matches jnp.argsort(-rand) stable ascending):
//   positions [0, n_inv): invalid slots ordered by rand DESC, ties idx ASC
//   positions [n_inv, L): valid slots in original index order
__global__ __launch_bounds__(LEN) void build_perm(const void* __restrict__ mask,
                                                  int* __restrict__ src,
                                                  int* __restrict__ dst,
                                                  int* __restrict__ ml_arr,
                                                  float* __restrict__ mask_out) {
  const int b = blockIdx.x;
  const int l = threadIdx.x;
  const int wave = l >> 6, lane = l & 63;
  __shared__ uint32_t inv_key[LEN];
  __shared__ int inv_idx[LEN];
  __shared__ int wsum[8];
  __shared__ int woff[9];

  // runtime mask-dtype detection: first element is always valid (len >= 256)
  const uint32_t w0 = ((const uint32_t*)mask)[0];
  bool valid;
  if (w0 == 1u) {                       // int32 0/1
    valid = ((const int*)mask)[b * LEN + l] != 0;
  } else if (w0 == 0x3F800000u) {       // float32 0.0/1.0
    valid = ((const float*)mask)[b * LEN + l] != 0.0f;
  } else {                              // 1-byte bool
    valid = ((const unsigned char*)mask)[b * LEN + l] != 0;
  }
  const bool inv = !valid;

  uint32_t o0, o1;
  threefry2x32_k042(0u, (uint32_t)(b * LEN + l), o0, o1);
  const uint32_t bits = o0 ^ o1;
  const uint32_t ui = (bits >> 9) | 0x3F800000u;  // monotone in uniform value

  // order-preserving compaction of invalid slots
  const unsigned long long bal = __ballot(inv);
  const int lower = __popcll(bal & ((1ull << lane) - 1ull));
  if (lane == 0) wsum[wave] = __popcll(bal);
  __syncthreads();
  if (l == 0) {
    int acc = 0;
    for (int w = 0; w < 8; ++w) { woff[w] = acc; acc += wsum[w]; }
    woff[8] = acc;
  }
  __syncthreads();
  const int n_inv = woff[8];
  const int inv_before = woff[wave] + lower;  // # invalid with index < l
  if (inv) {
    inv_key[inv_before] = ui;
    inv_idx[inv_before] = l;
  }
  __syncthreads();

  int pos;
  if (inv) {
    int rank = 0;
    for (int j = 0; j < n_inv; ++j) {
      const uint32_t kj = inv_key[j];
      rank += (kj > ui || (kj == ui && inv_idx[j] < l)) ? 1 : 0;
    }
    pos = rank;
  } else {
    pos = n_inv + (l - inv_before);  // valid slots keep original order
  }
  src[b * LEN + pos] = l;
  dst[b * LEN + l] = pos;            // inverse permutation

  const int nv = LEN - n_inv;
  const int ml = nv < 1 ? 1 : nv;
  if (l == 0) ml_arr[b] = ml;
  mask_out[b * LEN + l] = (l >= n_inv && l < ml) ? 1.0f : 0.0f;
}

// ---------------- Kernel 2: uu + fused x/v gather ----------------
// uu[b,c,i,j]_out = uu[b,c,src[i],src[j]]  <=>  for input row i':
//   out[b,c,dst[i'], j] = in[b,c,i',src[j]]
// Reads stream perfectly sequentially (block reads 32 consecutive input
// rows = 64KB contiguous); column gather via wave-private LDS row; writes
// are full 2KB rows at permuted row offsets (fire-and-forget).
// No barriers in the row loop; depth-2 register prefetch.
// Tail: block (b,k) also emits x channel k (and v channel k if k<4).
__global__ __launch_bounds__(256) void uu_perm(const float* __restrict__ in,
                                               float* __restrict__ out,
                                               const float* __restrict__ xin,
                                               const float* __restrict__ vin,
                                               float* __restrict__ xout,
                                               float* __restrict__ vout,
                                               const int* __restrict__ src,
                                               const int* __restrict__ dst,
                                               const int* __restrict__ ml_arr) {
  __shared__ int s_src[LEN];
  __shared__ float s_row[4][LEN];
  const int tid = threadIdx.x;
  const int wave = tid >> 6, lane = tid & 63;
  const int b = blockIdx.x >> 6;               // 64 blocks per batch sample
  const int k = blockIdx.x & 63;
  const int irow0 = blockIdx.x * 32 + wave * 8;  // global input row id
  const int i0 = irow0 & (LEN - 1);              // row within plane
  const long plane = (long)(irow0 & ~(LEN - 1)) * LEN;

  for (int t = tid; t < LEN; t += 256) s_src[t] = src[b * LEN + t];
  __syncthreads();  // the only barrier

  // column gather sources (same for all rows) -> registers
  int c[8];
#pragma unroll
  for (int kk = 0; kk < 8; ++kk) c[kk] = s_src[lane * 8 + kk];
  // destination rows for my 8 sequential input rows (uniform, L2 broadcast)
  int dr[8];
#pragma unroll
  for (int r = 0; r < 8; ++r) dr[r] = dst[b * LEN + i0 + r];

  float* myrow = &s_row[wave][0];
  const float* ip = in + plane + (long)i0 * LEN + lane * 8;

  // depth-2 pipeline: row r+1 loads issue before row r's LDS/gather/store
  f4 a0 = *(const f4*)(ip);
  f4 a1 = *(const f4*)(ip + 4);
#pragma unroll
  for (int r = 0; r < 8; ++r) {
    f4 b0, b1;
    if (r < 7) {
      b0 = *(const f4*)(ip + (long)(r + 1) * LEN);
      b1 = *(const f4*)(ip + (long)(r + 1) * LEN + 4);
    }
    *(f4*)(myrow + lane * 8) = a0;
    *(f4*)(myrow + lane * 8 + 4) = a1;
    f4 q0, q1;
    q0.x = myrow[c[0]]; q0.y = myrow[c[1]]; q0.z = myrow[c[2]]; q0.w = myrow[c[3]];
    q1.x = myrow[c[4]]; q1.y = myrow[c[5]]; q1.z = myrow[c[6]]; q1.w = myrow[c[7]];
    f4* op = (f4*)(out + plane + (long)dr[r] * LEN + lane * 8);
    op[0] = q0;
    op[1] = q1;
    a0 = b0; a1 = b1;
  }

  // ---- fused x/v gather + trim for this (b, k) ----
  const int ml = ml_arr[b];
  {
    const float* xrow = xin + (long)((b << 6) + k) * LEN;
    float* orow = xout + (long)((b << 6) + k) * LEN;
    for (int p = tid; p < LEN; p += 256) {
      orow[p] = (p < ml) ? xrow[s_src[p]] : 0.0f;
    }
  }
  if (k < NCV) {
    const float* vrow = vin + (long)((b << 2) + k) * LEN;
    float* orow = vout + (long)((b << 2) + k) * LEN;
    for (int p = tid; p < LEN; p += 256) {
      orow[p] = (p < ml) ? vrow[s_src[p]] : 0.0f;
    }
  }
}

extern "C" void kernel_launch(void* const* d_in, const int* in_sizes, int n_in,
                              void* d_out, int out_size, void* d_ws, size_t ws_size,
                              hipStream_t stream) {
  const float* x  = (const float*)d_in[0];   // (64,64,512)
  const float* v  = (const float*)d_in[1];   // (64,4,512)
  const float* uu = (const float*)d_in[2];   // (64,4,512,512)
  const void*  mask = d_in[3];               // (64,1,512)

  float* out   = (float*)d_out;
  float* out_x = out;                        // 2,097,152
  float* out_v = out + 2097152;              // 131,072
  float* out_m = out + 2228224;              // 32,768
  float* out_u = out + 2260992;              // 67,108,864

  int* src = (int*)d_ws;                     // 64*512 ints
  int* dst = src + NB * LEN;                 // 64*512 ints
  int* ml  = dst + NB * LEN;                 // 64 ints

  build_perm<<<NB, LEN, 0, stream>>>(mask, src, dst, ml, out_m);

  uu_perm<<<(NB * NCU * LEN) / 32, 256, 0, stream>>>(
      uu, out_u, x, v, out_x, out_v, src, dst, ml);
}